// Round 9
// baseline (283.403 us; speedup 1.0000x reference)
//
#include <hip/hip_runtime.h>
#include <cstdint>
#include <cstddef>

#define NN 100000
#define D 128
#define K2 256  // GEMM K: [h | neigh]

typedef __attribute__((ext_vector_type(8))) short bf16x8;
typedef __attribute__((ext_vector_type(4))) float f32x4;

__device__ inline float bfhi2f(unsigned int u) {
    union { unsigned int i; float f; } v; v.i = u & 0xffff0000u; return v.f;
}
__device__ inline float bflo2f(unsigned int u) {
    union { unsigned int i; float f; } v; v.i = u << 16; return v.f;
}
__device__ inline unsigned short f2bf(float f) {  // RNE
    union { float f; unsigned int i; } v; v.f = f;
    unsigned int r = v.i + 0x7FFFu + ((v.i >> 16) & 1u);
    return (unsigned short)(r >> 16);
}

// ---------------- degree ----------------
__global__ void k_deg(const int* __restrict__ dst, int ne, int* __restrict__ deg) {
    int e = blockIdx.x * blockDim.x + threadIdx.x;
    if (e < ne) atomicAdd(&deg[dst[e]], 1);
}

// ---------------- scan: per-chunk reduce ----------------
__global__ void k_chunk_reduce(const int* __restrict__ deg, int n, int* __restrict__ bsum) {
    __shared__ int s[256];
    int i = blockIdx.x * 256 + threadIdx.x;
    s[threadIdx.x] = (i < n) ? deg[i] : 0;
    __syncthreads();
    for (int off = 128; off > 0; off >>= 1) {
        if (threadIdx.x < off) s[threadIdx.x] += s[threadIdx.x + off];
        __syncthreads();
    }
    if (threadIdx.x == 0) bsum[blockIdx.x] = s[0];
}

// ---------------- scan of partials: one block (nb <= 512) ----------------
__global__ __launch_bounds__(512) void k_scan_partials(int* __restrict__ bsum, int nb,
                                                       int* __restrict__ rowptr, int n) {
    __shared__ int s[512];
    int tid = threadIdx.x;
    int v = (tid < nb) ? bsum[tid] : 0;
    s[tid] = v;
    __syncthreads();
    for (int off = 1; off < 512; off <<= 1) {
        int t = (tid >= off) ? s[tid - off] : 0;
        __syncthreads();
        s[tid] += t;
        __syncthreads();
    }
    if (tid < nb) bsum[tid] = s[tid] - v;
    if (tid == nb - 1) rowptr[n] = s[tid];
}

// ---------------- per-chunk exclusive scan + invdeg + cursor init ----------------
__global__ void k_chunk_scan(const int* __restrict__ deg, int n, const int* __restrict__ bsum,
                             int* __restrict__ rowptr, int* __restrict__ cursor,
                             float* __restrict__ invd) {
    __shared__ int s[256];
    int tid = threadIdx.x;
    int i = blockIdx.x * 256 + tid;
    int v = (i < n) ? deg[i] : 0;
    s[tid] = v;
    __syncthreads();
    for (int off = 1; off < 256; off <<= 1) {
        int t = (tid >= off) ? s[tid - off] : 0;
        __syncthreads();
        s[tid] += t;
        __syncthreads();
    }
    if (i < n) {
        int excl = bsum[blockIdx.x] + s[tid] - v;
        rowptr[i] = excl;
        cursor[i] = excl;  // k_fill bumps this directly
        invd[i] = 1.0f / fmaxf((float)v, 1.0f);
    }
}

// ---------------- CSR fill (cursor pre-seeded with rowptr) ----------------
__global__ void k_fill(const int* __restrict__ src, const int* __restrict__ dst, int ne,
                       int* __restrict__ cursor, int* __restrict__ col) {
    int e = blockIdx.x * blockDim.x + threadIdx.x;
    if (e < ne) {
        int p = atomicAdd(&cursor[dst[e]], 1);
        col[p] = src[e];
    }
}

// ---------------- prep: h -> Ht bf16, weights -> Btf frag-order, zero deg ----------------
#define T_H   (NN * 32)          // 3,200,000
#define T_BT  (3 * 128 * K2)     // 98,304
#define T_Z   (NN / 4)           // 25,000 int4 stores
__global__ void k_prep(const float* __restrict__ h, const float* __restrict__ Ws,
                       const float* __restrict__ Wn, unsigned short* __restrict__ Ht,
                       unsigned short* __restrict__ Btf, int4* __restrict__ degz) {
    int t = blockIdx.x * 256 + threadIdx.x;
    if (t < T_H) {
        int row = t >> 5, c4 = (t & 31) << 2;
        float4 v = *(const float4*)(h + (size_t)row * D + c4);
        ushort4 o = make_ushort4(f2bf(v.x), f2bf(v.y), f2bf(v.z), f2bf(v.w));
        *(ushort4*)(Ht + (size_t)row * D + c4) = o;
    } else if (t < T_H + T_BT) {
        int t2 = t - T_H;
        int j = t2 & 7; int rest = t2 >> 3;
        int lane = rest & 63; rest >>= 6;
        int ks = rest & 7; rest >>= 3;
        int nf = rest & 7; int l = rest >> 3;
        int nn = nf * 16 + (lane & 15);
        int k = ks * 32 + (lane >> 4) * 8 + j;
        float v = (k < D) ? Ws[(size_t)l * D * D + (size_t)k * D + nn]
                          : Wn[(size_t)l * D * D + (size_t)(k - D) * D + nn];
        Btf[t2] = f2bf(v);
    } else {
        int t3 = t - T_H - T_BT;
        if (t3 < T_Z) degz[t3] = make_int4(0, 0, 0, 0);
    }
}

// ---------------- mean aggregation: one wave per node, paired-dwordx2 gather ----------------
// Lanes 0-31 fetch even edges' rows (8B/lane), lanes 32-63 odd edges. Row loads are
// PREDICATED on slot liveness (half-wave-uniform exec branch) so no duplicate fetches;
// dead slots accumulate pre-zeroed registers. Even/odd partials merge via shfl_xor(32).
__global__ __launch_bounds__(256) void k_agg(const unsigned short* __restrict__ Ht,
                                             unsigned short* __restrict__ Nt,
                                             const int* __restrict__ rowptr,
                                             const int* __restrict__ col,
                                             const float* __restrict__ invd) {
    int node = (blockIdx.x * 256 + threadIdx.x) >> 6;
    int lane = threadIdx.x & 63;
    if (node >= NN) return;
    int e0 = rowptr[node];
    int n = rowptr[node + 1] - e0;
    int half = lane >> 5;        // 0 = even edge of pair, 1 = odd
    int coff = (lane & 31) * 4;  // 4 channels per lane
    float a0 = 0.f, a1 = 0.f, a2 = 0.f, a3 = 0.f;
    for (int base = 0; base < n; base += 8) {
        int rem = n - base;      // >= 1
        int idx = lane & 7;
        int cv = col[e0 + base + (idx < rem ? idx : rem - 1)];  // clamped, one load
        uint2 u[4];
#pragma unroll
        for (int p = 0; p < 4; ++p) {
            uint2 t = make_uint2(0u, 0u);
            if (2 * p + half < rem) {  // half-wave-uniform: masked half skips the fetch
                int si = __shfl(cv, 2 * p + half, 64);
                t = *(const uint2*)(Ht + (size_t)si * D + coff);
            }
            u[p] = t;
        }
#pragma unroll
        for (int p = 0; p < 4; ++p) {
            a0 += bflo2f(u[p].x); a1 += bfhi2f(u[p].x);
            a2 += bflo2f(u[p].y); a3 += bfhi2f(u[p].y);
        }
    }
    a0 += __shfl_xor(a0, 32, 64);
    a1 += __shfl_xor(a1, 32, 64);
    a2 += __shfl_xor(a2, 32, 64);
    a3 += __shfl_xor(a3, 32, 64);
    if (half == 0) {
        float inv = invd[node];
        uint2 o;
        o.x = ((unsigned int)f2bf(a1 * inv) << 16) | f2bf(a0 * inv);
        o.y = ((unsigned int)f2bf(a3 * inv) << 16) | f2bf(a2 * inv);
        *(uint2*)(Nt + (size_t)node * D + coff) = o;
    }
}

// ---------------- MFMA GEMM: [64 rows x K2] @ W^T -> [64 x 128] per block ----------------
// 4 waves; wave w owns n-fragments {w, w+4} -> B stays in registers (loaded once).
// A-tile staged to LDS via global_load_lds (linear dest) with XOR-swizzled global source;
// ds_read_b128 a-frags apply the same XOR -> conflict-free (2 lanes/bank).
__global__ __launch_bounds__(256, 3) void k_gemm(const unsigned short* __restrict__ Ht,
                                                 const unsigned short* __restrict__ Btf,
                                                 const float* __restrict__ bias,
                                                 unsigned short* __restrict__ HtW,
                                                 float* __restrict__ outf,
                                                 int relu, int M) {
    __shared__ unsigned short Alds[64 * K2];  // 32 KB, rows of 512B: [h(256B) | neigh(256B)]
    int wid = threadIdx.x >> 6;
    int lane = threadIdx.x & 63;
    int r16 = lane & 15;
    int g = lane >> 4;
    int m0 = blockIdx.x * 64;

    // B fragments in registers: wave w -> nf = w and w+4, all 8 k-slices
    bf16x8 bfr[2][8];
#pragma unroll
    for (int q = 0; q < 2; ++q) {
        int nf = wid + q * 4;
#pragma unroll
        for (int ks = 0; ks < 8; ++ks)
            bfr[q][ks] = *(const bf16x8*)(Btf + (size_t)(((nf * 8 + ks) << 6) + lane) * 8);
    }

    // stage A-tile: 32 x 1KB issues, 8 per wave. dest linear, source XOR-swizzled.
#pragma unroll
    for (int i = 0; i < 8; ++i) {
        int chunk = wid * 8 + i;
        int o = chunk * 1024 + lane * 16;
        int row = o >> 9;
        int half = (o >> 8) & 1;
        int cb = o & 255;
        int scb = cb ^ ((row & 7) << 4);
        const unsigned short* gsrc = Ht + (size_t)(m0 + row) * D + (size_t)half * ((size_t)NN * D) + (scb >> 1);
        __builtin_amdgcn_global_load_lds(
            (const __attribute__((address_space(1))) unsigned int*)gsrc,
            (__attribute__((address_space(3))) unsigned int*)((char*)Alds + chunk * 1024),
            16, 0, 0);
    }
    __syncthreads();

    f32x4 acc[4][2];
#pragma unroll
    for (int mt = 0; mt < 4; ++mt)
#pragma unroll
        for (int q = 0; q < 2; ++q) acc[mt][q] = (f32x4){0.f, 0.f, 0.f, 0.f};

#pragma unroll
    for (int mt = 0; mt < 4; ++mt) {
        int row = mt * 16 + r16;
        bf16x8 a[8];
#pragma unroll
        for (int ks = 0; ks < 8; ++ks) {
            int kb = (ks * 32 + g * 8) * 2;           // byte col in 512B row
            int c = kb ^ ((row & 7) << 4);
            a[ks] = *(const bf16x8*)((const char*)Alds + row * 512 + c);
        }
#pragma unroll
        for (int ks = 0; ks < 8; ++ks) {
            acc[mt][0] = __builtin_amdgcn_mfma_f32_16x16x32_bf16(a[ks], bfr[0][ks], acc[mt][0], 0, 0, 0);
            acc[mt][1] = __builtin_amdgcn_mfma_f32_16x16x32_bf16(a[ks], bfr[1][ks], acc[mt][1], 0, 0, 0);
        }
    }

    // epilogue: D-frag row = g*4+i, col = r16 (within 16x16)
    float bv[2];
    bv[0] = bias[wid * 16 + r16];
    bv[1] = bias[(wid + 4) * 16 + r16];
#pragma unroll
    for (int mt = 0; mt < 4; ++mt) {
#pragma unroll
        for (int q = 0; q < 2; ++q) {
            int colc = (wid + q * 4) * 16 + r16;
#pragma unroll
            for (int i = 0; i < 4; ++i) {
                int row = m0 + mt * 16 + g * 4 + i;
                if (row >= M) continue;
                float v = acc[mt][q][i] + bv[q];
                if (relu) v = fmaxf(v, 0.f);
                if (outf) outf[(size_t)row * D + colc] = v;
                else HtW[(size_t)row * D + colc] = f2bf(v);
            }
        }
    }
}

extern "C" void kernel_launch(void* const* d_in, const int* in_sizes, int n_in,
                              void* d_out, int out_size, void* d_ws, size_t ws_size,
                              hipStream_t stream) {
    const float* h = (const float*)d_in[0];
    const int* src = (const int*)d_in[1];
    const int* dst = (const int*)d_in[2];
    const float* Ws = (const float*)d_in[3];
    const float* Wn = (const float*)d_in[4];
    const float* b = (const float*)d_in[5];
    float* out = (float*)d_out;
    int ne = in_sizes[1];

    // workspace: Ht and Nt adjacent (gemm stages with one base + half*NN*D offset)
    char* ws = (char*)d_ws;
    unsigned short* Ht = (unsigned short*)ws; ws += (size_t)NN * D * sizeof(unsigned short);  // 25.6 MB
    unsigned short* Nt = (unsigned short*)ws; ws += (size_t)NN * D * sizeof(unsigned short);  // 25.6 MB
    int* col = (int*)ws;    ws += (size_t)ne * sizeof(int);                                   // 2.56 MB
    unsigned short* Btf = (unsigned short*)ws; ws += (size_t)3 * 128 * K2 * sizeof(unsigned short);
    int* deg = (int*)ws;    ws += (size_t)NN * sizeof(int);
    int* cursor = (int*)ws; ws += (size_t)NN * sizeof(int);
    int* rowptr = (int*)ws; ws += ((size_t)(NN + 1) * sizeof(int) + 15) / 16 * 16;
    int* bsum = (int*)ws;   ws += 512 * sizeof(int);
    float* invd = (float*)ws;

    int nchunk = (NN + 255) / 256;  // 391
    int nprep = (T_H + T_BT + T_Z + 255) / 256;
    k_prep<<<nprep, 256, 0, stream>>>(h, Ws, Wn, Ht, Btf, (int4*)deg);  // also zeros deg
    k_deg<<<(ne + 255) / 256, 256, 0, stream>>>(dst, ne, deg);
    k_chunk_reduce<<<nchunk, 256, 0, stream>>>(deg, NN, bsum);
    k_scan_partials<<<1, 512, 0, stream>>>(bsum, nchunk, rowptr, NN);
    k_chunk_scan<<<nchunk, 256, 0, stream>>>(deg, NN, bsum, rowptr, cursor, invd);
    k_fill<<<(ne + 255) / 256, 256, 0, stream>>>(src, dst, ne, cursor, col);

    int ngemm = (NN + 63) / 64;  // 1563
    for (int layer = 0; layer < 3; ++layer) {
        k_agg<<<(NN + 3) / 4, 256, 0, stream>>>(Ht, Nt, rowptr, col, invd);
        k_gemm<<<ngemm, 256, 0, stream>>>(Ht, Btf + (size_t)layer * 128 * K2, b + (size_t)layer * D,
                                          Ht, (layer == 2) ? out : nullptr, (layer < 2) ? 1 : 0, NN);
    }
}

// Round 10
// 263.138 us; speedup vs baseline: 1.0770x; 1.0770x over previous
//
#include <hip/hip_runtime.h>
#include <cstdint>
#include <cstddef>

#define NN 100000
#define D 128
#define K2 256  // GEMM K: [h | neigh]

typedef __attribute__((ext_vector_type(8))) short bf16x8;
typedef __attribute__((ext_vector_type(4))) float f32x4;

__device__ inline float bfhi2f(unsigned int u) {
    union { unsigned int i; float f; } v; v.i = u & 0xffff0000u; return v.f;
}
__device__ inline float bflo2f(unsigned int u) {
    union { unsigned int i; float f; } v; v.i = u << 16; return v.f;
}
__device__ inline unsigned short f2bf(float f) {  // RNE
    union { float f; unsigned int i; } v; v.f = f;
    unsigned int r = v.i + 0x7FFFu + ((v.i >> 16) & 1u);
    return (unsigned short)(r >> 16);
}

// ---------------- degree ----------------
__global__ void k_deg(const int* __restrict__ dst, int ne, int* __restrict__ deg) {
    int e = blockIdx.x * blockDim.x + threadIdx.x;
    if (e < ne) atomicAdd(&deg[dst[e]], 1);
}

// ---------------- scan: per-chunk reduce ----------------
__global__ void k_chunk_reduce(const int* __restrict__ deg, int n, int* __restrict__ bsum) {
    __shared__ int s[256];
    int i = blockIdx.x * 256 + threadIdx.x;
    s[threadIdx.x] = (i < n) ? deg[i] : 0;
    __syncthreads();
    for (int off = 128; off > 0; off >>= 1) {
        if (threadIdx.x < off) s[threadIdx.x] += s[threadIdx.x + off];
        __syncthreads();
    }
    if (threadIdx.x == 0) bsum[blockIdx.x] = s[0];
}

// ---------------- scan of partials: one block (nb <= 512) ----------------
__global__ __launch_bounds__(512) void k_scan_partials(int* __restrict__ bsum, int nb,
                                                       int* __restrict__ rowptr, int n) {
    __shared__ int s[512];
    int tid = threadIdx.x;
    int v = (tid < nb) ? bsum[tid] : 0;
    s[tid] = v;
    __syncthreads();
    for (int off = 1; off < 512; off <<= 1) {
        int t = (tid >= off) ? s[tid - off] : 0;
        __syncthreads();
        s[tid] += t;
        __syncthreads();
    }
    if (tid < nb) bsum[tid] = s[tid] - v;
    if (tid == nb - 1) rowptr[n] = s[tid];
}

// ---------------- per-chunk exclusive scan + invdeg + cursor init ----------------
__global__ void k_chunk_scan(const int* __restrict__ deg, int n, const int* __restrict__ bsum,
                             int* __restrict__ rowptr, int* __restrict__ cursor,
                             float* __restrict__ invd) {
    __shared__ int s[256];
    int tid = threadIdx.x;
    int i = blockIdx.x * 256 + tid;
    int v = (i < n) ? deg[i] : 0;
    s[tid] = v;
    __syncthreads();
    for (int off = 1; off < 256; off <<= 1) {
        int t = (tid >= off) ? s[tid - off] : 0;
        __syncthreads();
        s[tid] += t;
        __syncthreads();
    }
    if (i < n) {
        int excl = bsum[blockIdx.x] + s[tid] - v;
        rowptr[i] = excl;
        cursor[i] = excl;  // k_fill bumps this directly
        invd[i] = 1.0f / fmaxf((float)v, 1.0f);
    }
}

// ---------------- CSR fill (cursor pre-seeded with rowptr) ----------------
__global__ void k_fill(const int* __restrict__ src, const int* __restrict__ dst, int ne,
                       int* __restrict__ cursor, int* __restrict__ col) {
    int e = blockIdx.x * blockDim.x + threadIdx.x;
    if (e < ne) {
        int p = atomicAdd(&cursor[dst[e]], 1);
        col[p] = src[e];
    }
}

// ---------------- prep: h -> Ht bf16, weights -> Btf frag-order, zero deg ----------------
#define T_H   (NN * 32)          // 3,200,000
#define T_BT  (3 * 128 * K2)     // 98,304
#define T_Z   (NN / 4)           // 25,000 int4 stores
__global__ void k_prep(const float* __restrict__ h, const float* __restrict__ Ws,
                       const float* __restrict__ Wn, unsigned short* __restrict__ Ht,
                       unsigned short* __restrict__ Btf, int4* __restrict__ degz) {
    int t = blockIdx.x * 256 + threadIdx.x;
    if (t < T_H) {
        int row = t >> 5, c4 = (t & 31) << 2;
        float4 v = *(const float4*)(h + (size_t)row * D + c4);
        ushort4 o = make_ushort4(f2bf(v.x), f2bf(v.y), f2bf(v.z), f2bf(v.w));
        *(ushort4*)(Ht + (size_t)row * D + c4) = o;
    } else if (t < T_H + T_BT) {
        int t2 = t - T_H;
        int j = t2 & 7; int rest = t2 >> 3;
        int lane = rest & 63; rest >>= 6;
        int ks = rest & 7; rest >>= 3;
        int nf = rest & 7; int l = rest >> 3;
        int nn = nf * 16 + (lane & 15);
        int k = ks * 32 + (lane >> 4) * 8 + j;
        float v = (k < D) ? Ws[(size_t)l * D * D + (size_t)k * D + nn]
                          : Wn[(size_t)l * D * D + (size_t)(k - D) * D + nn];
        Btf[t2] = f2bf(v);
    } else {
        int t3 = t - T_H - T_BT;
        if (t3 < T_Z) degz[t3] = make_int4(0, 0, 0, 0);
    }
}

// ---------------- mean aggregation: one wave per node, dwordx4 4-edge gather ----------------
// 16 lanes x 16B = one 256B row -> ONE load instruction covers FOUR edges.
// Per 8-edge group: 1 col load + 2 row loads (2nd skipped wave-uniformly if rem<=4).
// Dead slots masked in registers (no exec-mask branches - round-9 lesson).
// Slot-reduce via shfl_xor(16,32); lanes 0-15 store the output row as one uint4.
__global__ __launch_bounds__(256) void k_agg(const unsigned short* __restrict__ Ht,
                                             unsigned short* __restrict__ Nt,
                                             const int* __restrict__ rowptr,
                                             const int* __restrict__ col,
                                             const float* __restrict__ invd) {
    int node = (blockIdx.x * 256 + threadIdx.x) >> 6;
    int lane = threadIdx.x & 63;
    if (node >= NN) return;
    int e0 = rowptr[node];
    int n = rowptr[node + 1] - e0;
    float inv = invd[node];
    int slot = lane >> 4;        // which edge of the 4-pack
    int coff = (lane & 15) * 8;  // 8 channels (16B) per lane
    float a0 = 0.f, a1 = 0.f, a2 = 0.f, a3 = 0.f, a4 = 0.f, a5 = 0.f, a6 = 0.f, a7 = 0.f;
    for (int base = 0; base < n; base += 8) {
        int rem = n - base;      // >= 1, wave-uniform
        int idx = lane & 7;
        int cv = col[e0 + base + (idx < rem ? idx : rem - 1)];  // clamped, one load
        // pack 0: edges base+0..3
        {
            int si = __shfl(cv, slot, 64);
            uint4 u = *(const uint4*)(Ht + (size_t)si * D + coff);
            bool live = slot < rem;
            unsigned int ux = live ? u.x : 0u, uy = live ? u.y : 0u;
            unsigned int uz = live ? u.z : 0u, uw = live ? u.w : 0u;
            a0 += bflo2f(ux); a1 += bfhi2f(ux);
            a2 += bflo2f(uy); a3 += bfhi2f(uy);
            a4 += bflo2f(uz); a5 += bfhi2f(uz);
            a6 += bflo2f(uw); a7 += bfhi2f(uw);
        }
        // pack 1: edges base+4..7 (wave-uniform skip: s_cbranch, no divergence)
        if (rem > 4) {
            int si = __shfl(cv, 4 + slot, 64);
            uint4 u = *(const uint4*)(Ht + (size_t)si * D + coff);
            bool live = 4 + slot < rem;
            unsigned int ux = live ? u.x : 0u, uy = live ? u.y : 0u;
            unsigned int uz = live ? u.z : 0u, uw = live ? u.w : 0u;
            a0 += bflo2f(ux); a1 += bfhi2f(ux);
            a2 += bflo2f(uy); a3 += bfhi2f(uy);
            a4 += bflo2f(uz); a5 += bfhi2f(uz);
            a6 += bflo2f(uw); a7 += bfhi2f(uw);
        }
    }
    // reduce the 4 slots (lanes differing in bits 4-5 hold same channels)
    a0 += __shfl_xor(a0, 16, 64); a0 += __shfl_xor(a0, 32, 64);
    a1 += __shfl_xor(a1, 16, 64); a1 += __shfl_xor(a1, 32, 64);
    a2 += __shfl_xor(a2, 16, 64); a2 += __shfl_xor(a2, 32, 64);
    a3 += __shfl_xor(a3, 16, 64); a3 += __shfl_xor(a3, 32, 64);
    a4 += __shfl_xor(a4, 16, 64); a4 += __shfl_xor(a4, 32, 64);
    a5 += __shfl_xor(a5, 16, 64); a5 += __shfl_xor(a5, 32, 64);
    a6 += __shfl_xor(a6, 16, 64); a6 += __shfl_xor(a6, 32, 64);
    a7 += __shfl_xor(a7, 16, 64); a7 += __shfl_xor(a7, 32, 64);
    if (slot == 0) {  // lanes 0-15 write the full 256B row
        uint4 o;
        o.x = ((unsigned int)f2bf(a1 * inv) << 16) | f2bf(a0 * inv);
        o.y = ((unsigned int)f2bf(a3 * inv) << 16) | f2bf(a2 * inv);
        o.z = ((unsigned int)f2bf(a5 * inv) << 16) | f2bf(a4 * inv);
        o.w = ((unsigned int)f2bf(a7 * inv) << 16) | f2bf(a6 * inv);
        *(uint4*)(Nt + (size_t)node * D + coff) = o;
    }
}

// ---------------- MFMA GEMM: [64 rows x K2] @ W^T -> [64 x 128] per block ----------------
// 4 waves; wave w owns n-fragments {w, w+4} -> B stays in registers (loaded once).
// A-tile staged to LDS via global_load_lds (linear dest) with XOR-swizzled global source;
// ds_read_b128 a-frags apply the same XOR -> conflict-free (2 lanes/bank).
__global__ __launch_bounds__(256, 3) void k_gemm(const unsigned short* __restrict__ Ht,
                                                 const unsigned short* __restrict__ Btf,
                                                 const float* __restrict__ bias,
                                                 unsigned short* __restrict__ HtW,
                                                 float* __restrict__ outf,
                                                 int relu, int M) {
    __shared__ unsigned short Alds[64 * K2];  // 32 KB, rows of 512B: [h(256B) | neigh(256B)]
    int wid = threadIdx.x >> 6;
    int lane = threadIdx.x & 63;
    int r16 = lane & 15;
    int g = lane >> 4;
    int m0 = blockIdx.x * 64;

    // B fragments in registers: wave w -> nf = w and w+4, all 8 k-slices
    bf16x8 bfr[2][8];
#pragma unroll
    for (int q = 0; q < 2; ++q) {
        int nf = wid + q * 4;
#pragma unroll
        for (int ks = 0; ks < 8; ++ks)
            bfr[q][ks] = *(const bf16x8*)(Btf + (size_t)(((nf * 8 + ks) << 6) + lane) * 8);
    }

    // stage A-tile: 32 x 1KB issues, 8 per wave. dest linear, source XOR-swizzled.
#pragma unroll
    for (int i = 0; i < 8; ++i) {
        int chunk = wid * 8 + i;
        int o = chunk * 1024 + lane * 16;
        int row = o >> 9;
        int half = (o >> 8) & 1;
        int cb = o & 255;
        int scb = cb ^ ((row & 7) << 4);
        const unsigned short* gsrc = Ht + (size_t)(m0 + row) * D + (size_t)half * ((size_t)NN * D) + (scb >> 1);
        __builtin_amdgcn_global_load_lds(
            (const __attribute__((address_space(1))) unsigned int*)gsrc,
            (__attribute__((address_space(3))) unsigned int*)((char*)Alds + chunk * 1024),
            16, 0, 0);
    }
    __syncthreads();

    f32x4 acc[4][2];
#pragma unroll
    for (int mt = 0; mt < 4; ++mt)
#pragma unroll
        for (int q = 0; q < 2; ++q) acc[mt][q] = (f32x4){0.f, 0.f, 0.f, 0.f};

#pragma unroll
    for (int mt = 0; mt < 4; ++mt) {
        int row = mt * 16 + r16;
        bf16x8 a[8];
#pragma unroll
        for (int ks = 0; ks < 8; ++ks) {
            int kb = (ks * 32 + g * 8) * 2;           // byte col in 512B row
            int c = kb ^ ((row & 7) << 4);
            a[ks] = *(const bf16x8*)((const char*)Alds + row * 512 + c);
        }
#pragma unroll
        for (int ks = 0; ks < 8; ++ks) {
            acc[mt][0] = __builtin_amdgcn_mfma_f32_16x16x32_bf16(a[ks], bfr[0][ks], acc[mt][0], 0, 0, 0);
            acc[mt][1] = __builtin_amdgcn_mfma_f32_16x16x32_bf16(a[ks], bfr[1][ks], acc[mt][1], 0, 0, 0);
        }
    }

    // epilogue: D-frag row = g*4+i, col = r16 (within 16x16)
    float bv[2];
    bv[0] = bias[wid * 16 + r16];
    bv[1] = bias[(wid + 4) * 16 + r16];
#pragma unroll
    for (int mt = 0; mt < 4; ++mt) {
#pragma unroll
        for (int q = 0; q < 2; ++q) {
            int colc = (wid + q * 4) * 16 + r16;
#pragma unroll
            for (int i = 0; i < 4; ++i) {
                int row = m0 + mt * 16 + g * 4 + i;
                if (row >= M) continue;
                float v = acc[mt][q][i] + bv[q];
                if (relu) v = fmaxf(v, 0.f);
                if (outf) outf[(size_t)row * D + colc] = v;
                else HtW[(size_t)row * D + colc] = f2bf(v);
            }
        }
    }
}

extern "C" void kernel_launch(void* const* d_in, const int* in_sizes, int n_in,
                              void* d_out, int out_size, void* d_ws, size_t ws_size,
                              hipStream_t stream) {
    const float* h = (const float*)d_in[0];
    const int* src = (const int*)d_in[1];
    const int* dst = (const int*)d_in[2];
    const float* Ws = (const float*)d_in[3];
    const float* Wn = (const float*)d_in[4];
    const float* b = (const float*)d_in[5];
    float* out = (float*)d_out;
    int ne = in_sizes[1];

    // workspace: Ht and Nt adjacent (gemm stages with one base + half*NN*D offset)
    char* ws = (char*)d_ws;
    unsigned short* Ht = (unsigned short*)ws; ws += (size_t)NN * D * sizeof(unsigned short);  // 25.6 MB
    unsigned short* Nt = (unsigned short*)ws; ws += (size_t)NN * D * sizeof(unsigned short);  // 25.6 MB
    int* col = (int*)ws;    ws += (size_t)ne * sizeof(int);                                   // 2.56 MB
    unsigned short* Btf = (unsigned short*)ws; ws += (size_t)3 * 128 * K2 * sizeof(unsigned short);
    int* deg = (int*)ws;    ws += (size_t)NN * sizeof(int);
    int* cursor = (int*)ws; ws += (size_t)NN * sizeof(int);
    int* rowptr = (int*)ws; ws += ((size_t)(NN + 1) * sizeof(int) + 15) / 16 * 16;
    int* bsum = (int*)ws;   ws += 512 * sizeof(int);
    float* invd = (float*)ws;

    int nchunk = (NN + 255) / 256;  // 391
    int nprep = (T_H + T_BT + T_Z + 255) / 256;
    k_prep<<<nprep, 256, 0, stream>>>(h, Ws, Wn, Ht, Btf, (int4*)deg);  // also zeros deg
    k_deg<<<(ne + 255) / 256, 256, 0, stream>>>(dst, ne, deg);
    k_chunk_reduce<<<nchunk, 256, 0, stream>>>(deg, NN, bsum);
    k_scan_partials<<<1, 512, 0, stream>>>(bsum, nchunk, rowptr, NN);
    k_chunk_scan<<<nchunk, 256, 0, stream>>>(deg, NN, bsum, rowptr, cursor, invd);
    k_fill<<<(ne + 255) / 256, 256, 0, stream>>>(src, dst, ne, cursor, col);

    int ngemm = (NN + 63) / 64;  // 1563
    for (int layer = 0; layer < 3; ++layer) {
        k_agg<<<(NN + 3) / 4, 256, 0, stream>>>(Ht, Nt, rowptr, col, invd);
        k_gemm<<<ngemm, 256, 0, stream>>>(Ht, Btf + (size_t)layer * 128 * K2, b + (size_t)layer * D,
                                          Ht, (layer == 2) ? out : nullptr, (layer < 2) ? 1 : 0, NN);
    }
}

// Round 11
// 231.547 us; speedup vs baseline: 1.2240x; 1.1364x over previous
//
#include <hip/hip_runtime.h>
#include <cstdint>
#include <cstddef>

#define NN 100000
#define D 128
#define K2 256  // GEMM K: [h | neigh]

typedef __attribute__((ext_vector_type(8))) short bf16x8;
typedef __attribute__((ext_vector_type(4))) float f32x4;

__device__ inline float bfhi2f(unsigned int u) {
    union { unsigned int i; float f; } v; v.i = u & 0xffff0000u; return v.f;
}
__device__ inline float bflo2f(unsigned int u) {
    union { unsigned int i; float f; } v; v.i = u << 16; return v.f;
}
__device__ inline unsigned short f2bf(float f) {  // RNE
    union { float f; unsigned int i; } v; v.f = f;
    unsigned int r = v.i + 0x7FFFu + ((v.i >> 16) & 1u);
    return (unsigned short)(r >> 16);
}

// ---------------- degree ----------------
__global__ void k_deg(const int* __restrict__ dst, int ne, int* __restrict__ deg) {
    int e = blockIdx.x * blockDim.x + threadIdx.x;
    if (e < ne) atomicAdd(&deg[dst[e]], 1);
}

// ---------------- scan: per-chunk reduce ----------------
__global__ void k_chunk_reduce(const int* __restrict__ deg, int n, int* __restrict__ bsum) {
    __shared__ int s[256];
    int i = blockIdx.x * 256 + threadIdx.x;
    s[threadIdx.x] = (i < n) ? deg[i] : 0;
    __syncthreads();
    for (int off = 128; off > 0; off >>= 1) {
        if (threadIdx.x < off) s[threadIdx.x] += s[threadIdx.x + off];
        __syncthreads();
    }
    if (threadIdx.x == 0) bsum[blockIdx.x] = s[0];
}

// ---------------- scan of partials: one block (nb <= 512) ----------------
__global__ __launch_bounds__(512) void k_scan_partials(int* __restrict__ bsum, int nb,
                                                       int* __restrict__ rowptr, int n) {
    __shared__ int s[512];
    int tid = threadIdx.x;
    int v = (tid < nb) ? bsum[tid] : 0;
    s[tid] = v;
    __syncthreads();
    for (int off = 1; off < 512; off <<= 1) {
        int t = (tid >= off) ? s[tid - off] : 0;
        __syncthreads();
        s[tid] += t;
        __syncthreads();
    }
    if (tid < nb) bsum[tid] = s[tid] - v;
    if (tid == nb - 1) rowptr[n] = s[tid];
}

// ---------------- per-chunk exclusive scan + invdeg + cursor init ----------------
__global__ void k_chunk_scan(const int* __restrict__ deg, int n, const int* __restrict__ bsum,
                             int* __restrict__ rowptr, int* __restrict__ cursor,
                             float* __restrict__ invd) {
    __shared__ int s[256];
    int tid = threadIdx.x;
    int i = blockIdx.x * 256 + tid;
    int v = (i < n) ? deg[i] : 0;
    s[tid] = v;
    __syncthreads();
    for (int off = 1; off < 256; off <<= 1) {
        int t = (tid >= off) ? s[tid - off] : 0;
        __syncthreads();
        s[tid] += t;
        __syncthreads();
    }
    if (i < n) {
        int excl = bsum[blockIdx.x] + s[tid] - v;
        rowptr[i] = excl;
        cursor[i] = excl;  // k_fill bumps this directly
        invd[i] = 1.0f / fmaxf((float)v, 1.0f);
    }
}

// ---------------- CSR fill (cursor pre-seeded with rowptr) ----------------
__global__ void k_fill(const int* __restrict__ src, const int* __restrict__ dst, int ne,
                       int* __restrict__ cursor, int* __restrict__ col) {
    int e = blockIdx.x * blockDim.x + threadIdx.x;
    if (e < ne) {
        int p = atomicAdd(&cursor[dst[e]], 1);
        col[p] = src[e];
    }
}

// ---------------- prep: h -> Ht bf16, weights -> Btf frag-order, zero deg ----------------
#define T_H   (NN * 32)          // 3,200,000
#define T_BT  (3 * 128 * K2)     // 98,304
#define T_Z   (NN / 4)           // 25,000 int4 stores
__global__ void k_prep(const float* __restrict__ h, const float* __restrict__ Ws,
                       const float* __restrict__ Wn, unsigned short* __restrict__ Ht,
                       unsigned short* __restrict__ Btf, int4* __restrict__ degz) {
    int t = blockIdx.x * 256 + threadIdx.x;
    if (t < T_H) {
        int row = t >> 5, c4 = (t & 31) << 2;
        float4 v = *(const float4*)(h + (size_t)row * D + c4);
        ushort4 o = make_ushort4(f2bf(v.x), f2bf(v.y), f2bf(v.z), f2bf(v.w));
        *(ushort4*)(Ht + (size_t)row * D + c4) = o;
    } else if (t < T_H + T_BT) {
        int t2 = t - T_H;
        int j = t2 & 7; int rest = t2 >> 3;
        int lane = rest & 63; rest >>= 6;
        int ks = rest & 7; rest >>= 3;
        int nf = rest & 7; int l = rest >> 3;
        int nn = nf * 16 + (lane & 15);
        int k = ks * 32 + (lane >> 4) * 8 + j;
        float v = (k < D) ? Ws[(size_t)l * D * D + (size_t)k * D + nn]
                          : Wn[(size_t)l * D * D + (size_t)(k - D) * D + nn];
        Btf[t2] = f2bf(v);
    } else {
        int t3 = t - T_H - T_BT;
        if (t3 < T_Z) degz[t3] = make_int4(0, 0, 0, 0);
    }
}

// ---------------- mean aggregation: FOUR nodes per wave, one 16-lane group each ----------------
// Group g (lanes g*16..g*16+15) owns node wave*4+g: 8 channels (16B) per lane.
// Per 16-edge chunk: 1 col load; edges processed 8 at a time as independent dwordx4
// loads (one wave-instruction = 4 rows, one per group). Group-local accumulation ->
// NO cross-lane reduce; store is one wave-wide dwordx4 covering all 4 nodes.
// Group-divergent loop bounds are exec-masked (no if/else around loads).
__global__ __launch_bounds__(256) void k_agg(const unsigned short* __restrict__ Ht,
                                             unsigned short* __restrict__ Nt,
                                             const int* __restrict__ rowptr,
                                             const int* __restrict__ col,
                                             const float* __restrict__ invd) {
    int wave = (blockIdx.x * 256 + threadIdx.x) >> 6;  // 25000 waves exactly
    int lane = threadIdx.x & 63;
    int g = lane >> 4;
    int lane16 = lane & 15;
    int node = wave * 4 + g;                            // < NN always (100000 = 25000*4)
    int e0 = rowptr[node];
    int n = rowptr[node + 1] - e0;
    float inv = invd[node];
    int coff = lane16 * 8;                              // 8 channels (16B) per lane
    float a0 = 0.f, a1 = 0.f, a2 = 0.f, a3 = 0.f, a4 = 0.f, a5 = 0.f, a6 = 0.f, a7 = 0.f;
    for (int base = 0; base < n; base += 16) {
        int rem = n - base;                             // group-uniform, >= 1
        int lim = rem < 16 ? rem : 16;
        int cidx = lane16 < rem ? lane16 : rem - 1;
        int cv = col[e0 + base + cidx];                 // 16 edges of this group
        for (int j = 0; j < lim; j += 8) {
            uint4 u[8];
#pragma unroll
            for (int k = 0; k < 8; ++k) {
                int ee = j + k;
                int eidx = ee < lim ? ee : lim - 1;     // clamp: dup loads are cache-hot
                int si = __shfl(cv, (g << 4) + eidx, 64);
                u[k] = *(const uint4*)(Ht + (size_t)si * D + coff);
            }
#pragma unroll
            for (int k = 0; k < 8; ++k) {
                bool live = (j + k) < lim;
                unsigned int ux = live ? u[k].x : 0u, uy = live ? u[k].y : 0u;
                unsigned int uz = live ? u[k].z : 0u, uw = live ? u[k].w : 0u;
                a0 += bflo2f(ux); a1 += bfhi2f(ux);
                a2 += bflo2f(uy); a3 += bfhi2f(uy);
                a4 += bflo2f(uz); a5 += bfhi2f(uz);
                a6 += bflo2f(uw); a7 += bfhi2f(uw);
            }
        }
    }
    uint4 o;
    o.x = ((unsigned int)f2bf(a1 * inv) << 16) | f2bf(a0 * inv);
    o.y = ((unsigned int)f2bf(a3 * inv) << 16) | f2bf(a2 * inv);
    o.z = ((unsigned int)f2bf(a5 * inv) << 16) | f2bf(a4 * inv);
    o.w = ((unsigned int)f2bf(a7 * inv) << 16) | f2bf(a6 * inv);
    *(uint4*)(Nt + (size_t)node * D + coff) = o;        // 64 lanes = 4 full rows
}

// ---------------- MFMA GEMM: [64 rows x K2] @ W^T -> [64 x 128] per block ----------------
// 4 waves; wave w owns n-fragments {w, w+4} -> B stays in registers (loaded once).
// A-tile staged to LDS via global_load_lds (linear dest) with XOR-swizzled global source;
// ds_read_b128 a-frags apply the same XOR -> conflict-free (2 lanes/bank).
__global__ __launch_bounds__(256, 3) void k_gemm(const unsigned short* __restrict__ Ht,
                                                 const unsigned short* __restrict__ Btf,
                                                 const float* __restrict__ bias,
                                                 unsigned short* __restrict__ HtW,
                                                 float* __restrict__ outf,
                                                 int relu, int M) {
    __shared__ unsigned short Alds[64 * K2];  // 32 KB, rows of 512B: [h(256B) | neigh(256B)]
    int wid = threadIdx.x >> 6;
    int lane = threadIdx.x & 63;
    int r16 = lane & 15;
    int g = lane >> 4;
    int m0 = blockIdx.x * 64;

    // B fragments in registers: wave w -> nf = w and w+4, all 8 k-slices
    bf16x8 bfr[2][8];
#pragma unroll
    for (int q = 0; q < 2; ++q) {
        int nf = wid + q * 4;
#pragma unroll
        for (int ks = 0; ks < 8; ++ks)
            bfr[q][ks] = *(const bf16x8*)(Btf + (size_t)(((nf * 8 + ks) << 6) + lane) * 8);
    }

    // stage A-tile: 32 x 1KB issues, 8 per wave. dest linear, source XOR-swizzled.
#pragma unroll
    for (int i = 0; i < 8; ++i) {
        int chunk = wid * 8 + i;
        int o = chunk * 1024 + lane * 16;
        int row = o >> 9;
        int half = (o >> 8) & 1;
        int cb = o & 255;
        int scb = cb ^ ((row & 7) << 4);
        const unsigned short* gsrc = Ht + (size_t)(m0 + row) * D + (size_t)half * ((size_t)NN * D) + (scb >> 1);
        __builtin_amdgcn_global_load_lds(
            (const __attribute__((address_space(1))) unsigned int*)gsrc,
            (__attribute__((address_space(3))) unsigned int*)((char*)Alds + chunk * 1024),
            16, 0, 0);
    }
    __syncthreads();

    f32x4 acc[4][2];
#pragma unroll
    for (int mt = 0; mt < 4; ++mt)
#pragma unroll
        for (int q = 0; q < 2; ++q) acc[mt][q] = (f32x4){0.f, 0.f, 0.f, 0.f};

#pragma unroll
    for (int mt = 0; mt < 4; ++mt) {
        int row = mt * 16 + r16;
        bf16x8 a[8];
#pragma unroll
        for (int ks = 0; ks < 8; ++ks) {
            int kb = (ks * 32 + g * 8) * 2;           // byte col in 512B row
            int c = kb ^ ((row & 7) << 4);
            a[ks] = *(const bf16x8*)((const char*)Alds + row * 512 + c);
        }
#pragma unroll
        for (int ks = 0; ks < 8; ++ks) {
            acc[mt][0] = __builtin_amdgcn_mfma_f32_16x16x32_bf16(a[ks], bfr[0][ks], acc[mt][0], 0, 0, 0);
            acc[mt][1] = __builtin_amdgcn_mfma_f32_16x16x32_bf16(a[ks], bfr[1][ks], acc[mt][1], 0, 0, 0);
        }
    }

    // epilogue: D-frag row = g*4+i, col = r16 (within 16x16)
    float bv[2];
    bv[0] = bias[wid * 16 + r16];
    bv[1] = bias[(wid + 4) * 16 + r16];
#pragma unroll
    for (int mt = 0; mt < 4; ++mt) {
#pragma unroll
        for (int q = 0; q < 2; ++q) {
            int colc = (wid + q * 4) * 16 + r16;
#pragma unroll
            for (int i = 0; i < 4; ++i) {
                int row = m0 + mt * 16 + g * 4 + i;
                if (row >= M) continue;
                float v = acc[mt][q][i] + bv[q];
                if (relu) v = fmaxf(v, 0.f);
                if (outf) outf[(size_t)row * D + colc] = v;
                else HtW[(size_t)row * D + colc] = f2bf(v);
            }
        }
    }
}

extern "C" void kernel_launch(void* const* d_in, const int* in_sizes, int n_in,
                              void* d_out, int out_size, void* d_ws, size_t ws_size,
                              hipStream_t stream) {
    const float* h = (const float*)d_in[0];
    const int* src = (const int*)d_in[1];
    const int* dst = (const int*)d_in[2];
    const float* Ws = (const float*)d_in[3];
    const float* Wn = (const float*)d_in[4];
    const float* b = (const float*)d_in[5];
    float* out = (float*)d_out;
    int ne = in_sizes[1];

    // workspace: Ht and Nt adjacent (gemm stages with one base + half*NN*D offset)
    char* ws = (char*)d_ws;
    unsigned short* Ht = (unsigned short*)ws; ws += (size_t)NN * D * sizeof(unsigned short);  // 25.6 MB
    unsigned short* Nt = (unsigned short*)ws; ws += (size_t)NN * D * sizeof(unsigned short);  // 25.6 MB
    int* col = (int*)ws;    ws += (size_t)ne * sizeof(int);                                   // 2.56 MB
    unsigned short* Btf = (unsigned short*)ws; ws += (size_t)3 * 128 * K2 * sizeof(unsigned short);
    int* deg = (int*)ws;    ws += (size_t)NN * sizeof(int);
    int* cursor = (int*)ws; ws += (size_t)NN * sizeof(int);
    int* rowptr = (int*)ws; ws += ((size_t)(NN + 1) * sizeof(int) + 15) / 16 * 16;
    int* bsum = (int*)ws;   ws += 512 * sizeof(int);
    float* invd = (float*)ws;

    int nchunk = (NN + 255) / 256;  // 391
    int nprep = (T_H + T_BT + T_Z + 255) / 256;
    k_prep<<<nprep, 256, 0, stream>>>(h, Ws, Wn, Ht, Btf, (int4*)deg);  // also zeros deg
    k_deg<<<(ne + 255) / 256, 256, 0, stream>>>(dst, ne, deg);
    k_chunk_reduce<<<nchunk, 256, 0, stream>>>(deg, NN, bsum);
    k_scan_partials<<<1, 512, 0, stream>>>(bsum, nchunk, rowptr, NN);
    k_chunk_scan<<<nchunk, 256, 0, stream>>>(deg, NN, bsum, rowptr, cursor, invd);
    k_fill<<<(ne + 255) / 256, 256, 0, stream>>>(src, dst, ne, cursor, col);

    int nagg = (NN / 4 + 3) / 4;  // 25000 waves -> 6250 blocks
    int ngemm = (NN + 63) / 64;   // 1563
    for (int layer = 0; layer < 3; ++layer) {
        k_agg<<<nagg, 256, 0, stream>>>(Ht, Nt, rowptr, col, invd);
        k_gemm<<<ngemm, 256, 0, stream>>>(Ht, Btf + (size_t)layer * 128 * K2, b + (size_t)layer * D,
                                          Ht, (layer == 2) ? out : nullptr, (layer < 2) ? 1 : 0, NN);
    }
}

// Round 12
// 221.195 us; speedup vs baseline: 1.2812x; 1.0468x over previous
//
#include <hip/hip_runtime.h>
#include <cstdint>
#include <cstddef>

#define NN 100000
#define NPAD 100032   // 1563 blocks x 64 rows
#define D 128
#define K2 256        // GEMM K: [h | neigh]

typedef __attribute__((ext_vector_type(8))) short bf16x8;
typedef __attribute__((ext_vector_type(4))) float f32x4;

__device__ inline float bfhi2f(unsigned int u) {
    union { unsigned int i; float f; } v; v.i = u & 0xffff0000u; return v.f;
}
__device__ inline float bflo2f(unsigned int u) {
    union { unsigned int i; float f; } v; v.i = u << 16; return v.f;
}
__device__ inline unsigned short f2bf(float f) {  // RNE
    union { float f; unsigned int i; } v; v.f = f;
    unsigned int r = v.i + 0x7FFFu + ((v.i >> 16) & 1u);
    return (unsigned short)(r >> 16);
}

// ---------------- degree ----------------
__global__ void k_deg(const int* __restrict__ dst, int ne, int* __restrict__ deg) {
    int e = blockIdx.x * blockDim.x + threadIdx.x;
    if (e < ne) atomicAdd(&deg[dst[e]], 1);
}

// ---------------- scan: per-chunk reduce ----------------
__global__ void k_chunk_reduce(const int* __restrict__ deg, int n, int* __restrict__ bsum) {
    __shared__ int s[256];
    int i = blockIdx.x * 256 + threadIdx.x;
    s[threadIdx.x] = (i < n) ? deg[i] : 0;
    __syncthreads();
    for (int off = 128; off > 0; off >>= 1) {
        if (threadIdx.x < off) s[threadIdx.x] += s[threadIdx.x + off];
        __syncthreads();
    }
    if (threadIdx.x == 0) bsum[blockIdx.x] = s[0];
}

// ---------------- scan of partials: one block (nb <= 512) ----------------
__global__ __launch_bounds__(512) void k_scan_partials(int* __restrict__ bsum, int nb,
                                                       int* __restrict__ rowptr, int n) {
    __shared__ int s[512];
    int tid = threadIdx.x;
    int v = (tid < nb) ? bsum[tid] : 0;
    s[tid] = v;
    __syncthreads();
    for (int off = 1; off < 512; off <<= 1) {
        int t = (tid >= off) ? s[tid - off] : 0;
        __syncthreads();
        s[tid] += t;
        __syncthreads();
    }
    if (tid < nb) bsum[tid] = s[tid] - v;
    if (tid == nb - 1) rowptr[n] = s[tid];
}

// ---------------- per-chunk exclusive scan + invdeg + cursor init ----------------
__global__ void k_chunk_scan(const int* __restrict__ deg, int n, const int* __restrict__ bsum,
                             int* __restrict__ rowptr, int* __restrict__ cursor,
                             float* __restrict__ invd) {
    __shared__ int s[256];
    int tid = threadIdx.x;
    int i = blockIdx.x * 256 + tid;
    int v = (i < n) ? deg[i] : 0;
    s[tid] = v;
    __syncthreads();
    for (int off = 1; off < 256; off <<= 1) {
        int t = (tid >= off) ? s[tid - off] : 0;
        __syncthreads();
        s[tid] += t;
        __syncthreads();
    }
    if (i < n) {
        int excl = bsum[blockIdx.x] + s[tid] - v;
        rowptr[i] = excl;
        cursor[i] = excl;  // k_fill bumps this directly
        invd[i] = 1.0f / fmaxf((float)v, 1.0f);
    }
}

// ---------------- CSR fill (cursor pre-seeded with rowptr) ----------------
__global__ void k_fill(const int* __restrict__ src, const int* __restrict__ dst, int ne,
                       int* __restrict__ cursor, int* __restrict__ col) {
    int e = blockIdx.x * blockDim.x + threadIdx.x;
    if (e < ne) {
        int p = atomicAdd(&cursor[dst[e]], 1);
        col[p] = src[e];
    }
}

// ---------------- prep: h -> HtA bf16, weights -> Btf frag-order, zero deg ----------------
#define T_H   (NN * 32)          // 3,200,000
#define T_BT  (3 * 128 * K2)     // 98,304
#define T_Z   (NN / 4)           // 25,000 int4 stores
__global__ void k_prep(const float* __restrict__ h, const float* __restrict__ Ws,
                       const float* __restrict__ Wn, unsigned short* __restrict__ Ht,
                       unsigned short* __restrict__ Btf, int4* __restrict__ degz) {
    int t = blockIdx.x * 256 + threadIdx.x;
    if (t < T_H) {
        int row = t >> 5, c4 = (t & 31) << 2;
        float4 v = *(const float4*)(h + (size_t)row * D + c4);
        ushort4 o = make_ushort4(f2bf(v.x), f2bf(v.y), f2bf(v.z), f2bf(v.w));
        *(ushort4*)(Ht + (size_t)row * D + c4) = o;
    } else if (t < T_H + T_BT) {
        int t2 = t - T_H;
        int j = t2 & 7; int rest = t2 >> 3;
        int lane = rest & 63; rest >>= 6;
        int ks = rest & 7; rest >>= 3;
        int nf = rest & 7; int l = rest >> 3;
        int nn = nf * 16 + (lane & 15);
        int k = ks * 32 + (lane >> 4) * 8 + j;
        float v = (k < D) ? Ws[(size_t)l * D * D + (size_t)k * D + nn]
                          : Wn[(size_t)l * D * D + (size_t)(k - D) * D + nn];
        Btf[t2] = f2bf(v);
    } else {
        int t3 = t - T_H - T_BT;
        if (t3 < T_Z) degz[t3] = make_int4(0, 0, 0, 0);
    }
}

// ---------------- fused layer: gather 64 nodes -> LDS neigh half, h half via
// global_load_lds, then MFMA GEMM. Fusion v2: gather uses round-11's 4-parallel-
// node groups (4 serial chunks/wave, not 16 serial nodes - round-6 failure fix).
__global__ __launch_bounds__(256, 3) void k_layer(const unsigned short* __restrict__ Hin,
                                                  const unsigned short* __restrict__ Btf,
                                                  const float* __restrict__ bias,
                                                  const int* __restrict__ rowptr,
                                                  const int* __restrict__ col,
                                                  const float* __restrict__ invd,
                                                  unsigned short* __restrict__ Hout,
                                                  float* __restrict__ outf,
                                                  int relu) {
    __shared__ unsigned short Ah[64 * 128];  // 16 KB: h half, rows of 256B (swizzled)
    __shared__ unsigned short An[64 * 128];  // 16 KB: neigh half
    int wid = threadIdx.x >> 6;
    int lane = threadIdx.x & 63;
    int g = lane >> 4;
    int lane16 = lane & 15;
    int m0 = blockIdx.x * 64;

    // 1) issue h-half staging first: HBM latency hides under the gather.
    //    dest linear; source pre-swizzled (rule #21): physical byte p holds col p^swz
#pragma unroll
    for (int i = 0; i < 4; ++i) {
        int chunk = wid * 4 + i;
        int o = chunk * 1024 + lane * 16;
        int row = o >> 8;
        int cb = o & 255;
        int scb = cb ^ ((row & 7) << 4);
        const unsigned short* gsrc = Hin + (size_t)(m0 + row) * D + (scb >> 1);
        __builtin_amdgcn_global_load_lds(
            (const __attribute__((address_space(1))) unsigned int*)gsrc,
            (__attribute__((address_space(3))) unsigned int*)((char*)Ah + chunk * 1024),
            16, 0, 0);
    }

    // 2) gather: 4 chunks of 4 parallel nodes per wave (group-local accumulation,
    //    no cross-lane reduce). 8 independent dwordx4 row-loads in flight per batch.
    int coff = lane16 * 8;  // 8 channels (16B) per lane
    for (int c = 0; c < 4; ++c) {
        int row = wid * 16 + c * 4 + g;
        int node = m0 + row;
        int e0 = 0, n = 0;
        float inv = 0.f;
        if (node < NN) {
            e0 = rowptr[node];
            n = rowptr[node + 1] - e0;
            inv = invd[node];
        }
        float a0 = 0.f, a1 = 0.f, a2 = 0.f, a3 = 0.f, a4 = 0.f, a5 = 0.f, a6 = 0.f, a7 = 0.f;
        for (int base = 0; base < n; base += 16) {
            int rem = n - base;                         // group-uniform, >= 1
            int lim = rem < 16 ? rem : 16;
            int cidx = lane16 < rem ? lane16 : rem - 1;
            int cv = col[e0 + base + cidx];             // 16 edge ids of this group
            for (int j = 0; j < lim; j += 8) {
                uint4 u[8];
#pragma unroll
                for (int k = 0; k < 8; ++k) {
                    int ee = j + k;
                    int eidx = ee < lim ? ee : lim - 1; // clamp: dup loads cache-hot
                    int si = __shfl(cv, (g << 4) + eidx, 64);
                    u[k] = *(const uint4*)(Hin + (size_t)si * D + coff);
                }
#pragma unroll
                for (int k = 0; k < 8; ++k) {
                    bool live = (j + k) < lim;
                    unsigned int ux = live ? u[k].x : 0u, uy = live ? u[k].y : 0u;
                    unsigned int uz = live ? u[k].z : 0u, uw = live ? u[k].w : 0u;
                    a0 += bflo2f(ux); a1 += bfhi2f(ux);
                    a2 += bflo2f(uy); a3 += bfhi2f(uy);
                    a4 += bflo2f(uz); a5 += bfhi2f(uz);
                    a6 += bflo2f(uw); a7 += bfhi2f(uw);
                }
            }
        }
        uint4 o;
        o.x = ((unsigned int)f2bf(a1 * inv) << 16) | f2bf(a0 * inv);
        o.y = ((unsigned int)f2bf(a3 * inv) << 16) | f2bf(a2 * inv);
        o.z = ((unsigned int)f2bf(a5 * inv) << 16) | f2bf(a4 * inv);
        o.w = ((unsigned int)f2bf(a7 * inv) << 16) | f2bf(a6 * inv);
        int bo = row * 256 + ((lane16 * 16) ^ ((row & 7) << 4));  // same swizzle as Ah
        *(uint4*)((char*)An + bo) = o;
    }

    // 3) B fragments (after gather: keeps gather-phase register pressure low)
    bf16x8 bfr[2][8];
#pragma unroll
    for (int q = 0; q < 2; ++q) {
        int nf = wid + q * 4;
#pragma unroll
        for (int ks = 0; ks < 8; ++ks)
            bfr[q][ks] = *(const bf16x8*)(Btf + (size_t)(((nf * 8 + ks) << 6) + lane) * 8);
    }

    __syncthreads();  // drains global_load_lds + orders ds_writes

    // 4) MFMA: K = 256 = [h: ks 0..3 from Ah | neigh: ks 4..7 from An]
    f32x4 acc[4][2];
#pragma unroll
    for (int mt = 0; mt < 4; ++mt)
#pragma unroll
        for (int q = 0; q < 2; ++q) acc[mt][q] = (f32x4){0.f, 0.f, 0.f, 0.f};

#pragma unroll
    for (int mt = 0; mt < 4; ++mt) {
        int row = mt * 16 + lane16;
        int swz = (row & 7) << 4;
        bf16x8 a[8];
#pragma unroll
        for (int ks = 0; ks < 8; ++ks) {
            int kb = ks * 64 + g * 16;  // byte col in [0,512)
            const char* basep = (kb < 256) ? (const char*)Ah : (const char*)An;
            int cb2 = (kb & 255) ^ swz;
            a[ks] = *(const bf16x8*)(basep + row * 256 + cb2);
        }
#pragma unroll
        for (int ks = 0; ks < 8; ++ks) {
            acc[mt][0] = __builtin_amdgcn_mfma_f32_16x16x32_bf16(a[ks], bfr[0][ks], acc[mt][0], 0, 0, 0);
            acc[mt][1] = __builtin_amdgcn_mfma_f32_16x16x32_bf16(a[ks], bfr[1][ks], acc[mt][1], 0, 0, 0);
        }
    }

    // 5) epilogue: D-frag row = g*4+i, col = lane16 (within 16x16)
    float bv[2];
    bv[0] = bias[wid * 16 + lane16];
    bv[1] = bias[(wid + 4) * 16 + lane16];
#pragma unroll
    for (int mt = 0; mt < 4; ++mt) {
#pragma unroll
        for (int q = 0; q < 2; ++q) {
            int colc = (wid + q * 4) * 16 + lane16;
#pragma unroll
            for (int i = 0; i < 4; ++i) {
                int row = m0 + mt * 16 + g * 4 + i;
                if (row >= NN) continue;
                float v = acc[mt][q][i] + bv[q];
                if (relu) v = fmaxf(v, 0.f);
                if (outf) outf[(size_t)row * D + colc] = v;
                else Hout[(size_t)row * D + colc] = f2bf(v);
            }
        }
    }
}

extern "C" void kernel_launch(void* const* d_in, const int* in_sizes, int n_in,
                              void* d_out, int out_size, void* d_ws, size_t ws_size,
                              hipStream_t stream) {
    const float* h = (const float*)d_in[0];
    const int* src = (const int*)d_in[1];
    const int* dst = (const int*)d_in[2];
    const float* Ws = (const float*)d_in[3];
    const float* Wn = (const float*)d_in[4];
    const float* b = (const float*)d_in[5];
    float* out = (float*)d_out;
    int ne = in_sizes[1];

    // workspace (HtA/HtB padded to NPAD rows: tail-block staging stays in-bounds)
    char* ws = (char*)d_ws;
    unsigned short* HtA = (unsigned short*)ws; ws += (size_t)NPAD * D * sizeof(unsigned short);
    unsigned short* HtB = (unsigned short*)ws; ws += (size_t)NPAD * D * sizeof(unsigned short);
    int* col = (int*)ws;    ws += (size_t)ne * sizeof(int);
    unsigned short* Btf = (unsigned short*)ws; ws += (size_t)3 * 128 * K2 * sizeof(unsigned short);
    int* deg = (int*)ws;    ws += (size_t)NN * sizeof(int);
    int* cursor = (int*)ws; ws += (size_t)NN * sizeof(int);
    int* rowptr = (int*)ws; ws += ((size_t)(NN + 1) * sizeof(int) + 15) / 16 * 16;
    int* bsum = (int*)ws;   ws += 512 * sizeof(int);
    float* invd = (float*)ws;

    int nchunk = (NN + 255) / 256;  // 391
    int nprep = (T_H + T_BT + T_Z + 255) / 256;
    k_prep<<<nprep, 256, 0, stream>>>(h, Ws, Wn, HtA, Btf, (int4*)deg);  // also zeros deg
    k_deg<<<(ne + 255) / 256, 256, 0, stream>>>(dst, ne, deg);
    k_chunk_reduce<<<nchunk, 256, 0, stream>>>(deg, NN, bsum);
    k_scan_partials<<<1, 512, 0, stream>>>(bsum, nchunk, rowptr, NN);
    k_chunk_scan<<<nchunk, 256, 0, stream>>>(deg, NN, bsum, rowptr, cursor, invd);
    k_fill<<<(ne + 255) / 256, 256, 0, stream>>>(src, dst, ne, cursor, col);

    int ngrid = NPAD / 64;  // 1563
    // layer 0: HtA -> HtB ; layer 1: HtB -> HtA ; layer 2: HtA -> out (fp32)
    k_layer<<<ngrid, 256, 0, stream>>>(HtA, Btf, b, rowptr, col, invd,
                                       HtB, nullptr, 1);
    k_layer<<<ngrid, 256, 0, stream>>>(HtB, Btf + (size_t)1 * 128 * K2, b + 1 * D,
                                       rowptr, col, invd, HtA, nullptr, 1);
    k_layer<<<ngrid, 256, 0, stream>>>(HtA, Btf + (size_t)2 * 128 * K2, b + 2 * D,
                                       rowptr, col, invd, nullptr, out, 0);
}